// Round 1
// baseline (869.897 us; speedup 1.0000x reference)
//
#include <hip/hip_runtime.h>
#include <stdint.h>

// ---------------------------------------------------------------------------
// AstroSymbolicEpisodicLayer  (B=4, TQ=TK=2048, D=1024, R=64, H=512)
// bf16-MFMA decomposition; FFT binding done as DFT-table GEMMs.
// ---------------------------------------------------------------------------

#define Bq 4
#define Tq 2048
#define Dd 1024
#define NT 8192      // B*T
#define Hh 512
#define Rr_ 64
#define FP 640       // padded rfft freq count (513 -> 640, zero rows)
#define F2 1280      // 2*FP (re|im)

typedef unsigned short ushort_t;
typedef short s16x8 __attribute__((ext_vector_type(8)));
typedef float floatx4 __attribute__((ext_vector_type(4)));

__device__ __forceinline__ float b2f(ushort_t s) {
  unsigned u = (unsigned)s << 16;
  return __builtin_bit_cast(float, u);
}
__device__ __forceinline__ ushort_t f2b(float f) {
  unsigned u = __builtin_bit_cast(unsigned, f);
  unsigned r = (u + 0x7fffu + ((u >> 16) & 1u)) >> 16;
  return (ushort_t)r;
}

__device__ __forceinline__ void load_lds16(const void* g, void* l) {
  __builtin_amdgcn_global_load_lds((__attribute__((address_space(1))) void*)(g),
                                   (__attribute__((address_space(3))) void*)(l),
                                   16, 0, 0);
}

// ---------------------------------------------------------------------------
// GEMM: C[M,N] = A[M,K] @ Bt[N,K]^T (+bias) with optional epilogues.
// M,N multiples of 128; K multiple of 32. Block=256 (4 waves), tile 128x128.
// flags bit0 = relu. tau!=null => Epanechnikov score epilogue (v is cos_sim):
//   s = max(1 - tau[z]*0.25*(1-v)^2, 0), plus rowsum atomics if rowsum!=null.
// ---------------------------------------------------------------------------
__global__ __launch_bounds__(256) void gemm_bt(
    const ushort_t* __restrict__ A, const ushort_t* __restrict__ Bt,
    float* __restrict__ C, ushort_t* __restrict__ Cbf,
    const float* __restrict__ bias, const float* __restrict__ tau,
    float* __restrict__ rowsum, int rsStride,
    int K, int lda, int ldb, int ldc,
    long long sA, long long sB, long long sC, int flags)
{
  __shared__ __align__(16) ushort_t As[128 * 32];
  __shared__ __align__(16) ushort_t Bs[128 * 32];

  const int bz   = blockIdx.z;
  const ushort_t* Ab = A + (size_t)bz * sA;
  const ushort_t* Bb = Bt + (size_t)bz * sB;
  const int tm   = blockIdx.y * 128;
  const int tn   = blockIdx.x * 128;
  const int tid  = threadIdx.x;
  const int wave = tid >> 6;
  const int lane = tid & 63;
  const int wm   = (wave & 1) << 6;
  const int wn   = (wave >> 1) << 6;
  const int sr   = lane >> 2;          // staging row within 16
  const int sc   = (lane & 3) << 3;    // staging col elem (0,8,16,24)
  const int fr   = lane & 15;          // fragment row
  const int fk   = (lane >> 4) << 3;   // fragment k offset

  floatx4 acc[4][4] = {};

  for (int k0 = 0; k0 < K; k0 += 32) {
    // ---- global -> LDS staging (16B per lane, 2 passes of 64 rows) ----
    {
      const ushort_t* gA0 = Ab + (size_t)(tm + wave * 16 + sr) * lda + (k0 + sc);
      const ushort_t* gA1 = gA0 + (size_t)64 * lda;
      char* lA = (char*)As + wave * 1024;
      load_lds16(gA0, lA);
      load_lds16(gA1, lA + 4096);
      const ushort_t* gB0 = Bb + (size_t)(tn + wave * 16 + sr) * ldb + (k0 + sc);
      const ushort_t* gB1 = gB0 + (size_t)64 * ldb;
      char* lB = (char*)Bs + wave * 1024;
      load_lds16(gB0, lB);
      load_lds16(gB1, lB + 4096);
    }
    __syncthreads();
    s16x8 af[4], bfv[4];
#pragma unroll
    for (int i = 0; i < 4; i++)
      af[i] = *(const s16x8*)&As[(wm + i * 16 + fr) * 32 + fk];
#pragma unroll
    for (int j = 0; j < 4; j++)
      bfv[j] = *(const s16x8*)&Bs[(wn + j * 16 + fr) * 32 + fk];
#pragma unroll
    for (int i = 0; i < 4; i++)
#pragma unroll
      for (int j = 0; j < 4; j++)
        acc[i][j] = __builtin_amdgcn_mfma_f32_16x16x32_bf16(af[i], bfv[j], acc[i][j], 0, 0, 0);
    __syncthreads();
  }

  // ---- epilogue ----
  const float tv = tau ? tau[bz] : 0.f;
  float*   Cp  = C   ? C   + (size_t)bz * sC : nullptr;
  ushort_t* Cb = Cbf ? Cbf + (size_t)bz * sC : nullptr;
#pragma unroll
  for (int i = 0; i < 4; i++) {
#pragma unroll
    for (int r = 0; r < 4; r++) {
      const int row = tm + wm + i * 16 + (lane >> 4) * 4 + r;
      float rsum = 0.f;
#pragma unroll
      for (int j = 0; j < 4; j++) {
        const int col = tn + wn + j * 16 + (lane & 15);
        float v = acc[i][j][r];
        if (bias) v += bias[col];
        if (flags & 1) v = fmaxf(v, 0.f);
        if (tau) { float d = 1.0f - v; v = fmaxf(1.0f - tv * 0.25f * d * d, 0.f); }
        rsum += v;
        if (Cp) Cp[(size_t)row * ldc + col] = v;
        if (Cb) Cb[(size_t)row * ldc + col] = f2b(v);
      }
      if (rowsum) {
        rsum += __shfl_xor(rsum, 1);
        rsum += __shfl_xor(rsum, 2);
        rsum += __shfl_xor(rsum, 4);
        rsum += __shfl_xor(rsum, 8);
        if ((lane & 15) == 0)
          atomicAdd(&rowsum[(size_t)bz * rsStride + row], rsum);
      }
    }
  }
}

// ---------------------------------------------------------------------------
// small kernels
// ---------------------------------------------------------------------------
__global__ __launch_bounds__(256) void castbf(const float* __restrict__ in,
                                              ushort_t* __restrict__ out, int n4) {
  int i = blockIdx.x * 256 + threadIdx.x;
  if (i >= n4) return;
  float4 v = ((const float4*)in)[i];
  ushort4 o;
  o.x = f2b(v.x); o.y = f2b(v.y); o.z = f2b(v.z); o.w = f2b(v.w);
  ((ushort4*)out)[i] = o;
}

// out[c][r] = (c<Cc ? in[r][c] : 0), out has Cp rows. grid(Rr/32, Cp/32), block(32,8)
__global__ __launch_bounds__(256) void tcast(const float* __restrict__ in,
                                             ushort_t* __restrict__ out,
                                             int RrN, int Cc, int Cp) {
  __shared__ float t[32][33];
  int r0 = blockIdx.x * 32, c0 = blockIdx.y * 32;
  int x = threadIdx.x, y = threadIdx.y;
  for (int dy = 0; dy < 32; dy += 8) {
    int r = r0 + y + dy, c = c0 + x;
    t[y + dy][x] = (c < Cc) ? in[(size_t)r * Cc + c] : 0.f;
  }
  __syncthreads();
  for (int dy = 0; dy < 32; dy += 8) {
    int c = c0 + y + dy, r = r0 + x;
    if (c < Cp) out[(size_t)c * RrN + r] = f2b(t[x][y + dy]);
  }
}

// bf16 batched transpose: per z, in (RrN x Cc) -> out (Cc x RrN). grid(Cc/64, RrN/64, Z), block(64,8)
__global__ __launch_bounds__(512) void transpose_bf(const ushort_t* __restrict__ in,
                                                    ushort_t* __restrict__ out,
                                                    int RrN, int Cc, long long sIn, long long sOut) {
  __shared__ ushort_t t[64][65];
  int z = blockIdx.z;
  int r0 = blockIdx.y * 64, c0 = blockIdx.x * 64;
  int x = threadIdx.x, y = threadIdx.y;
  const ushort_t* ip = in + (size_t)z * sIn;
  ushort_t* op = out + (size_t)z * sOut;
  for (int dy = 0; dy < 64; dy += 8)
    t[y + dy][x] = ip[(size_t)(r0 + y + dy) * Cc + c0 + x];
  __syncthreads();
  for (int dy = 0; dy < 64; dy += 8)
    op[(size_t)(c0 + y + dy) * RrN + r0 + x] = t[x][y + dy];
}

// normalize role_matrix rows (64 x 1024) and write transposed bf16 (1024 x 64)
__global__ __launch_bounds__(256) void rolenorm(const float* __restrict__ rm,
                                                ushort_t* __restrict__ rmnT) {
  int r = blockIdx.x, tid = threadIdx.x;
  float4 v = ((const float4*)(rm + (size_t)r * 1024))[tid];
  float s = v.x * v.x + v.y * v.y + v.z * v.z + v.w * v.w;
#pragma unroll
  for (int m = 1; m < 64; m <<= 1) s += __shfl_xor(s, m);
  __shared__ float red[6];
  if ((tid & 63) == 0) red[tid >> 6] = s;
  __syncthreads();
  if (tid == 0) red[4] = 1.f / fmaxf(sqrtf(red[0] + red[1] + red[2] + red[3]), 1e-12f);
  __syncthreads();
  float inv = red[4];
  int d0 = tid * 4;
  float vv[4] = {v.x, v.y, v.z, v.w};
#pragma unroll
  for (int i = 0; i < 4; i++)
    rmnT[(size_t)(d0 + i) * 64 + r] = f2b(vv[i] * inv);
}

// row l2-normalize fp32 (rows x 1024) -> bf16; optional surprise accumulation
__global__ __launch_bounds__(256) void rownorm(const float* __restrict__ in,
                                               ushort_t* __restrict__ out,
                                               float* __restrict__ ssum, int tokPerBatch) {
  int row = blockIdx.x, tid = threadIdx.x;
  float4 v = ((const float4*)(in + (size_t)row * 1024))[tid];
  float s = v.x * v.x + v.y * v.y + v.z * v.z + v.w * v.w;
#pragma unroll
  for (int m = 1; m < 64; m <<= 1) s += __shfl_xor(s, m);
  __shared__ float red[6];
  if ((tid & 63) == 0) red[tid >> 6] = s;
  __syncthreads();
  if (tid == 0) {
    float nrm = sqrtf(red[0] + red[1] + red[2] + red[3]);
    red[4] = 1.f / fmaxf(nrm, 1e-12f);
    if (ssum) atomicAdd(&ssum[row / tokPerBatch], nrm);
  }
  __syncthreads();
  float inv = red[4];
  ushort4 o;
  o.x = f2b(v.x * inv); o.y = f2b(v.y * inv); o.z = f2b(v.z * inv); o.w = f2b(v.w * inv);
  ((ushort4*)(out + (size_t)row * 1024))[tid] = o;
}

__global__ void finalize_astro(const float* __restrict__ ssum, const float* __restrict__ astro,
                               const float* __restrict__ ascale, float* __restrict__ tau,
                               float* __restrict__ outTail) {
  int b = threadIdx.x;
  if (b < Bq) {
    float mean = ssum[b] * (1.f / (32.f * 2048.f));  // norm/sqrt(D), averaged over TQ
    float ns = 0.95f * astro[b] + 0.05f * mean;
    tau[b] = fmaxf(1.f + ascale[0] * ns, 0.001f);
    outTail[b] = ns;
  }
}

// softmax over 64 logits per row (logits stride 128), out bf16 (rows x 64)
__global__ __launch_bounds__(256) void softmax64(const float* __restrict__ logits,
                                                 ushort_t* __restrict__ out) {
  int row = blockIdx.x * 4 + (threadIdx.x >> 6);
  int lane = threadIdx.x & 63;
  float x = logits[(size_t)row * 128 + lane];
  float m = x;
#pragma unroll
  for (int s = 1; s < 64; s <<= 1) m = fmaxf(m, __shfl_xor(m, s));
  float e = expf(x - m);
  float sum = e;
#pragma unroll
  for (int s = 1; s < 64; s <<= 1) sum += __shfl_xor(sum, s);
  out[(size_t)row * 64 + lane] = f2b(e / sum);
}

// DFT tables. ftab: (1280 rows f|f+640, 1024 cols k): rows<640 cos(2pi f k/1024) (f<=512 else 0),
// rows>=640: -sin. itab: (1024 rows n, 1280 cols): w_f*cos / -w_f*sin, w in {1/1024, 2/1024}.
__global__ __launch_bounds__(256) void gen_ftab(ushort_t* __restrict__ ftab) {
  const float TW = 6.283185307179586f / 1024.f;
  int idx = blockIdx.x * 256 + threadIdx.x;
  int rowf = idx >> 10, k = idx & 1023;
  int f = rowf < FP ? rowf : rowf - FP;
  float v = 0.f;
  if (f <= 512) {
    float th = (float)((f * k) & 1023) * TW;
    float sv, cv; sincosf(th, &sv, &cv);
    v = (rowf < FP) ? cv : -sv;
  }
  ftab[idx] = f2b(v);
}
__global__ __launch_bounds__(256) void gen_itab(ushort_t* __restrict__ itab) {
  const float TW = 6.283185307179586f / 1024.f;
  int idx = blockIdx.x * 256 + threadIdx.x;
  int n = idx / F2;
  int c = idx - n * F2;
  int f = c < FP ? c : c - FP;
  float v = 0.f;
  if (f <= 512) {
    float w = (f == 0 || f == 512) ? (1.f / 1024.f) : (2.f / 1024.f);
    float th = (float)((f * n) & 1023) * TW;
    float sv, cv; sincosf(th, &sv, &cv);
    v = (c < FP) ? w * cv : -w * sv;
  }
  itab[idx] = f2b(v);
}

// pointwise complex product of spectra (bf16 in, bf16 out), layout [re(640)|im(640)]
__global__ __launch_bounds__(256) void fftmul(const ushort_t* __restrict__ KF,
                                              const ushort_t* __restrict__ RF,
                                              ushort_t* __restrict__ P) {
  int idx = blockIdx.x * 256 + threadIdx.x;   // [0, NT*FP)
  int t = idx / FP;
  int f = idx - t * FP;
  size_t base = (size_t)t * F2;
  float a = b2f(KF[base + f]), b = b2f(KF[base + FP + f]);
  float c = b2f(RF[base + f]), d = b2f(RF[base + FP + f]);
  P[base + f]      = f2b(a * c - b * d);
  P[base + FP + f] = f2b(a * d + b * c);
}

// in-place attn normalize: S[row, :] /= max(rowsum[row], 1e-9)
__global__ __launch_bounds__(256) void attn_norm(ushort_t* __restrict__ S,
                                                 const float* __restrict__ rowsum) {
  int gid = blockIdx.x * 256 + threadIdx.x;   // NT*2048/8 total
  int row = gid >> 8;
  int c0 = (gid & 255) << 3;
  float inv = 1.f / fmaxf(rowsum[row], 1e-9f);
  s16x8* p = (s16x8*)(S + (size_t)row * 2048 + c0);
  s16x8 v = *p;
  s16x8 o;
#pragma unroll
  for (int i = 0; i < 8; i++) o[i] = (short)f2b(b2f((ushort_t)v[i]) * inv);
  *p = o;
}

// ---------------------------------------------------------------------------
// workspace layout (bytes, all 256-aligned)
// ---------------------------------------------------------------------------
static constexpr size_t OFF_ROWSUM = 0;                    // 32768 (NT*4)
static constexpr size_t OFF_SSUM   = 32768;                // 16
static constexpr size_t OFF_TAU    = 32784;                // 16
static constexpr size_t OFF_WQT    = 33024;                // 2 MB each
static constexpr size_t OFF_WKT    = OFF_WQT + 2097152;
static constexpr size_t OFF_WVT    = OFF_WKT + 2097152;
static constexpr size_t OFF_WOT    = OFF_WVT + 2097152;
static constexpr size_t OFF_WR1T   = OFF_WOT + 2097152;    // 1 MB
static constexpr size_t OFF_WR2T   = OFF_WR1T + 1048576;   // 128x512 bf16
static constexpr size_t OFF_RMNT   = OFF_WR2T + 131072;    // 1024x64 bf16
static constexpr size_t OFF_FTAB   = OFF_RMNT + 131072;    // 1280x1024 bf16
static constexpr size_t OFF_ITAB   = OFF_FTAB + 2621440;   // 1024x1280 bf16
static constexpr size_t OFF_QBF    = OFF_ITAB + 2621440;   // NT*D bf16
static constexpr size_t OFF_KINBF  = OFF_QBF + 16777216;
static constexpr size_t OFF_VINBF  = OFF_KINBF + 16777216;
static constexpr size_t OFF_QF     = OFF_VINBF + 16777216; // NT*D fp32; later S_bf/attn (B*T*T bf16, same size)
static constexpr size_t OFF_KP     = OFF_QF + 33554432;    // NT*D bf16; [KP|VP] later reused as Kb fp32
static constexpr size_t OFF_VP     = OFF_KP + 16777216;
static constexpr size_t OFF_VT     = OFF_VP + 16777216;    // NT*D bf16 (per-batch transposed V)
static constexpr size_t OFF_HID    = OFF_VT + 16777216;    // NT*H bf16
static constexpr size_t OFF_LOGIT  = OFF_HID + 8388608;    // NT*128 fp32
static constexpr size_t OFF_RW     = OFF_LOGIT + 4194304;  // NT*64 bf16
static constexpr size_t OFF_RHO    = OFF_RW + 1048576;     // NT*D bf16
static constexpr size_t OFF_KF     = OFF_RHO + 16777216;   // NT*1280 bf16; later kn bf16
static constexpr size_t OFF_RF     = OFF_KF + 20971520;    // NT*1280 bf16; later ctx bf16
static constexpr size_t OFF_P      = OFF_RF + 20971520;    // NT*1280 bf16
static constexpr size_t OFF_QN     = OFF_P + 20971520;     // NT*D bf16
static constexpr size_t WS_NEEDED  = OFF_QN + 16777216;    // ~259.3 MB
static constexpr size_t OFF_S      = OFF_QF;   // scores/attn bf16 (B,2048,2048)
static constexpr size_t OFF_KB     = OFF_KP;   // K_bound fp32 (NT x 1024)
static constexpr size_t OFF_KN     = OFF_KF;   // k_n bf16
static constexpr size_t OFF_CTX    = OFF_RF;   // context bf16

static inline void launch_gemm(hipStream_t s, const ushort_t* A, const ushort_t* Bt,
                               float* C, ushort_t* Cbf, const float* bias, const float* tau,
                               float* rowsum, int rsStride,
                               int M, int N, int K, int lda, int ldb, int ldc,
                               long long sA, long long sB, long long sC, int Z, int flags) {
  dim3 g(N / 128, M / 128, Z), b(256);
  gemm_bt<<<g, b, 0, s>>>(A, Bt, C, Cbf, bias, tau, rowsum, rsStride,
                          K, lda, ldb, ldc, sA, sB, sC, flags);
}

extern "C" void kernel_launch(void* const* d_in, const int* in_sizes, int n_in,
                              void* d_out, int out_size, void* d_ws, size_t ws_size,
                              hipStream_t stream) {
  (void)in_sizes; (void)n_in; (void)out_size;
  if (ws_size < WS_NEEDED) return;  // not enough scratch; bail

  const float* q_in  = (const float*)d_in[0];
  const float* k_in  = (const float*)d_in[1];
  const float* v_in  = (const float*)d_in[2];
  const float* astro = (const float*)d_in[3];
  const float* Wq    = (const float*)d_in[4];
  const float* bq    = (const float*)d_in[5];
  const float* Wk    = (const float*)d_in[6];
  const float* bk    = (const float*)d_in[7];
  const float* Wv    = (const float*)d_in[8];
  const float* bv    = (const float*)d_in[9];
  const float* Wo    = (const float*)d_in[10];
  const float* bo    = (const float*)d_in[11];
  const float* roleM = (const float*)d_in[12];
  const float* Wr1   = (const float*)d_in[13];
  const float* br1   = (const float*)d_in[14];
  const float* Wr2   = (const float*)d_in[15];
  const float* ascl  = (const float*)d_in[16];

  char* ws = (char*)d_ws;
  float*    rowsum = (float*)(ws + OFF_ROWSUM);
  float*    ssum   = (float*)(ws + OFF_SSUM);
  float*    tau    = (float*)(ws + OFF_TAU);
  ushort_t* WqT  = (ushort_t*)(ws + OFF_WQT);
  ushort_t* WkT  = (ushort_t*)(ws + OFF_WKT);
  ushort_t* WvT  = (ushort_t*)(ws + OFF_WVT);
  ushort_t* WoT  = (ushort_t*)(ws + OFF_WOT);
  ushort_t* Wr1T = (ushort_t*)(ws + OFF_WR1T);
  ushort_t* Wr2T = (ushort_t*)(ws + OFF_WR2T);
  ushort_t* rmnT = (ushort_t*)(ws + OFF_RMNT);
  ushort_t* FTab = (ushort_t*)(ws + OFF_FTAB);
  ushort_t* ITab = (ushort_t*)(ws + OFF_ITAB);
  ushort_t* qbf  = (ushort_t*)(ws + OFF_QBF);
  ushort_t* kinb = (ushort_t*)(ws + OFF_KINBF);
  ushort_t* vinb = (ushort_t*)(ws + OFF_VINBF);
  float*    Qf   = (float*)(ws + OFF_QF);
  ushort_t* kp   = (ushort_t*)(ws + OFF_KP);
  ushort_t* vp   = (ushort_t*)(ws + OFF_VP);
  ushort_t* vT   = (ushort_t*)(ws + OFF_VT);
  ushort_t* hid  = (ushort_t*)(ws + OFF_HID);
  float*    logi = (float*)(ws + OFF_LOGIT);
  ushort_t* rw   = (ushort_t*)(ws + OFF_RW);
  ushort_t* rho  = (ushort_t*)(ws + OFF_RHO);
  ushort_t* KF   = (ushort_t*)(ws + OFF_KF);
  ushort_t* RF   = (ushort_t*)(ws + OFF_RF);
  ushort_t* Pb   = (ushort_t*)(ws + OFF_P);
  ushort_t* qn   = (ushort_t*)(ws + OFF_QN);
  ushort_t* Sb   = (ushort_t*)(ws + OFF_S);
  float*    Kb   = (float*)(ws + OFF_KB);
  ushort_t* kn   = (ushort_t*)(ws + OFF_KN);
  ushort_t* ctx  = (ushort_t*)(ws + OFF_CTX);
  float*    out  = (float*)d_out;

  // 0. zero accumulators (rowsum + ssum)
  hipMemsetAsync(ws + OFF_ROWSUM, 0, 32768 + 16, stream);

  // 1. cast inputs to bf16
  castbf<<<8192, 256, 0, stream>>>(q_in, qbf, NT * Dd / 4);
  castbf<<<8192, 256, 0, stream>>>(k_in, kinb, NT * Dd / 4);
  castbf<<<8192, 256, 0, stream>>>(v_in, vinb, NT * Dd / 4);

  // 2. weight transposes + tables
  tcast<<<dim3(32, 32), dim3(32, 8), 0, stream>>>(Wq, WqT, 1024, 1024, 1024);
  tcast<<<dim3(32, 32), dim3(32, 8), 0, stream>>>(Wk, WkT, 1024, 1024, 1024);
  tcast<<<dim3(32, 32), dim3(32, 8), 0, stream>>>(Wv, WvT, 1024, 1024, 1024);
  tcast<<<dim3(32, 32), dim3(32, 8), 0, stream>>>(Wo, WoT, 1024, 1024, 1024);
  tcast<<<dim3(32, 16), dim3(32, 8), 0, stream>>>(Wr1, Wr1T, 1024, 512, 512);
  tcast<<<dim3(16, 4),  dim3(32, 8), 0, stream>>>(Wr2, Wr2T, 512, 64, 128);
  rolenorm<<<64, 256, 0, stream>>>(roleM, rmnT);
  gen_ftab<<<(F2 * 1024) / 256, 256, 0, stream>>>(FTab);
  gen_itab<<<(1024 * F2) / 256, 256, 0, stream>>>(ITab);

  // 3. projections
  launch_gemm(stream, qbf, WqT, Qf, nullptr, bq, nullptr, nullptr, 0,
              NT, Dd, Dd, Dd, Dd, Dd, 0, 0, 0, 1, 0);
  launch_gemm(stream, kinb, WkT, nullptr, kp, bk, nullptr, nullptr, 0,
              NT, Dd, Dd, Dd, Dd, Dd, 0, 0, 0, 1, 0);
  launch_gemm(stream, vinb, WvT, nullptr, vp, bv, nullptr, nullptr, 0,
              NT, Dd, Dd, Dd, Dd, Dd, 0, 0, 0, 1, 0);

  // 4. q_n + surprise -> tau, new_state tail
  rownorm<<<NT, 256, 0, stream>>>(Qf, qn, ssum, Tq);
  finalize_astro<<<1, 64, 0, stream>>>(ssum, astro, ascl, tau, out + (size_t)NT * Dd);

  // 5. V transpose (per batch): (2048x1024) -> (1024x2048)
  transpose_bf<<<dim3(16, 32, Bq), dim3(64, 8), 0, stream>>>(
      vp, vT, Tq, Dd, (long long)Tq * Dd, (long long)Dd * Tq);

  // 6. role path
  launch_gemm(stream, kp, Wr1T, nullptr, hid, br1, nullptr, nullptr, 0,
              NT, Hh, Dd, Dd, Dd, Hh, 0, 0, 0, 1, 1 /*relu*/);
  launch_gemm(stream, hid, Wr2T, logi, nullptr, nullptr, nullptr, nullptr, 0,
              NT, 128, Hh, Hh, Hh, 128, 0, 0, 0, 1, 0);
  softmax64<<<NT / 4, 256, 0, stream>>>(logi, rw);
  launch_gemm(stream, rw, rmnT, nullptr, rho, nullptr, nullptr, nullptr, 0,
              NT, Dd, Rr_, Rr_, Rr_, Dd, 0, 0, 0, 1, 0);

  // 7. holographic binding via DFT-table GEMMs
  launch_gemm(stream, kp, FTab, nullptr, KF, nullptr, nullptr, nullptr, 0,
              NT, F2, Dd, Dd, Dd, F2, 0, 0, 0, 1, 0);
  launch_gemm(stream, rho, FTab, nullptr, RF, nullptr, nullptr, nullptr, 0,
              NT, F2, Dd, Dd, Dd, F2, 0, 0, 0, 1, 0);
  fftmul<<<(NT * FP) / 256, 256, 0, stream>>>(KF, RF, Pb);
  launch_gemm(stream, Pb, ITab, Kb, nullptr, nullptr, nullptr, nullptr, 0,
              NT, Dd, F2, F2, F2, Dd, 0, 0, 0, 1, 0);
  rownorm<<<NT, 256, 0, stream>>>(Kb, kn, nullptr, 1);

  // 8. attention: scores (Epanechnikov) + rowsum, normalize, context
  launch_gemm(stream, qn, kn, nullptr, Sb, nullptr, tau, rowsum, Tq,
              Tq, Tq, Dd, Dd, Dd, Tq,
              (long long)Tq * Dd, (long long)Tq * Dd, (long long)Tq * Tq, Bq, 0);
  attn_norm<<<(NT * Tq / 8) / 256, 256, 0, stream>>>(Sb, rowsum);
  launch_gemm(stream, Sb, vT, nullptr, ctx, nullptr, nullptr, nullptr, 0,
              Tq, Dd, Tq, Tq, Tq, Dd,
              (long long)Tq * Tq, (long long)Dd * Tq, (long long)Tq * Dd, Bq, 0);

  // 9. output projection -> d_out
  launch_gemm(stream, ctx, WoT, out, nullptr, bo, nullptr, nullptr, 0,
              NT, Dd, Dd, Dd, Dd, Dd, 0, 0, 0, 1, 0);
}

// Round 2
// 774.086 us; speedup vs baseline: 1.1238x; 1.1238x over previous
//
#include <hip/hip_runtime.h>
#include <stdint.h>

// ---------------------------------------------------------------------------
// AstroSymbolicEpisodicLayer  (B=4, TQ=TK=2048, D=1024, R=64, H=512)
// bf16-MFMA decomposition; FFT binding via DFT-table GEMMs.
// R2: epilogue-fused row norms, fused attn normalize, rfft(rho) = rw @ RFn.
// ---------------------------------------------------------------------------

#define Bq 4
#define Tq 2048
#define Dd 1024
#define NT 8192      // B*T
#define Hh 512
#define Rr_ 64
#define FP 640       // padded rfft freq count (513 -> 640, zero rows)
#define F2 1280      // 2*FP (re|im)

typedef unsigned short ushort_t;
typedef short s16x8 __attribute__((ext_vector_type(8)));
typedef float floatx4 __attribute__((ext_vector_type(4)));

__device__ __forceinline__ float b2f(ushort_t s) {
  unsigned u = (unsigned)s << 16;
  return __builtin_bit_cast(float, u);
}
__device__ __forceinline__ ushort_t f2b(float f) {
  unsigned u = __builtin_bit_cast(unsigned, f);
  unsigned r = (u + 0x7fffu + ((u >> 16) & 1u)) >> 16;
  return (ushort_t)r;
}

__device__ __forceinline__ void load_lds16(const void* g, void* l) {
  __builtin_amdgcn_global_load_lds((__attribute__((address_space(1))) void*)(g),
                                   (__attribute__((address_space(3))) void*)(l),
                                   16, 0, 0);
}

// ---------------------------------------------------------------------------
// GEMM: C[M,N] = A[M,K] @ Bt[N,K]^T (+bias), tile 128x128, 4 waves.
// flags bit0 = relu. tau!=null => Epanechnikov score transform.
// rsMode: 0 none; 1 atomicAdd row-sum(v); 2 atomicAdd row-sum(v^2);
//         3 divide v by rowsum[row] (read-only).
// ---------------------------------------------------------------------------
__global__ __launch_bounds__(256) void gemm_bt(
    const ushort_t* __restrict__ A, const ushort_t* __restrict__ Bt,
    float* __restrict__ C, ushort_t* __restrict__ Cbf,
    const float* __restrict__ bias, const float* __restrict__ tau,
    float* __restrict__ rowsum, int rsStride, int rsMode,
    int K, int lda, int ldb, int ldc,
    long long sA, long long sB, long long sC, int flags)
{
  __shared__ __align__(16) ushort_t As[128 * 32];
  __shared__ __align__(16) ushort_t Bs[128 * 32];

  const int bz   = blockIdx.z;
  const ushort_t* Ab = A + (size_t)bz * sA;
  const ushort_t* Bb = Bt + (size_t)bz * sB;
  const int tm   = blockIdx.y * 128;
  const int tn   = blockIdx.x * 128;
  const int tid  = threadIdx.x;
  const int wave = tid >> 6;
  const int lane = tid & 63;
  const int wm   = (wave & 1) << 6;
  const int wn   = (wave >> 1) << 6;
  const int sr   = lane >> 2;          // staging row within 16
  const int sc   = (lane & 3) << 3;    // staging col elem (0,8,16,24)
  const int fr   = lane & 15;          // fragment row
  const int fk   = (lane >> 4) << 3;   // fragment k offset

  floatx4 acc[4][4] = {};

  for (int k0 = 0; k0 < K; k0 += 32) {
    {
      const ushort_t* gA0 = Ab + (size_t)(tm + wave * 16 + sr) * lda + (k0 + sc);
      const ushort_t* gA1 = gA0 + (size_t)64 * lda;
      char* lA = (char*)As + wave * 1024;
      load_lds16(gA0, lA);
      load_lds16(gA1, lA + 4096);
      const ushort_t* gB0 = Bb + (size_t)(tn + wave * 16 + sr) * ldb + (k0 + sc);
      const ushort_t* gB1 = gB0 + (size_t)64 * ldb;
      char* lB = (char*)Bs + wave * 1024;
      load_lds16(gB0, lB);
      load_lds16(gB1, lB + 4096);
    }
    __syncthreads();
    s16x8 af[4], bfv[4];
#pragma unroll
    for (int i = 0; i < 4; i++)
      af[i] = *(const s16x8*)&As[(wm + i * 16 + fr) * 32 + fk];
#pragma unroll
    for (int j = 0; j < 4; j++)
      bfv[j] = *(const s16x8*)&Bs[(wn + j * 16 + fr) * 32 + fk];
#pragma unroll
    for (int i = 0; i < 4; i++)
#pragma unroll
      for (int j = 0; j < 4; j++)
        acc[i][j] = __builtin_amdgcn_mfma_f32_16x16x32_bf16(af[i], bfv[j], acc[i][j], 0, 0, 0);
    __syncthreads();
  }

  // ---- epilogue ----
  const float tv = tau ? tau[bz] : 0.f;
  float*   Cp  = C   ? C   + (size_t)bz * sC : nullptr;
  ushort_t* Cb = Cbf ? Cbf + (size_t)bz * sC : nullptr;
#pragma unroll
  for (int i = 0; i < 4; i++) {
#pragma unroll
    for (int r = 0; r < 4; r++) {
      const int row = tm + wm + i * 16 + (lane >> 4) * 4 + r;
      float rsum = 0.f;
      float dinv = 1.f;
      if (rsMode == 3)
        dinv = 1.f / fmaxf(rowsum[(size_t)bz * rsStride + row], 1e-9f);
#pragma unroll
      for (int j = 0; j < 4; j++) {
        const int col = tn + wn + j * 16 + (lane & 15);
        float v = acc[i][j][r];
        if (bias) v += bias[col];
        if (flags & 1) v = fmaxf(v, 0.f);
        if (tau) { float d = 1.0f - v; v = fmaxf(1.0f - tv * 0.25f * d * d, 0.f); }
        if (rsMode == 3) v *= dinv;
        rsum += (rsMode == 2) ? v * v : v;
        if (Cp) Cp[(size_t)row * ldc + col] = v;
        if (Cb) Cb[(size_t)row * ldc + col] = f2b(v);
      }
      if (rsMode == 1 || rsMode == 2) {
        rsum += __shfl_xor(rsum, 1);
        rsum += __shfl_xor(rsum, 2);
        rsum += __shfl_xor(rsum, 4);
        rsum += __shfl_xor(rsum, 8);
        if ((lane & 15) == 0)
          atomicAdd(&rowsum[(size_t)bz * rsStride + row], rsum);
      }
    }
  }
}

// ---------------------------------------------------------------------------
// small kernels
// ---------------------------------------------------------------------------
__global__ __launch_bounds__(256) void castbf(const float* __restrict__ in,
                                              ushort_t* __restrict__ out, int n4) {
  int i = blockIdx.x * 256 + threadIdx.x;
  if (i >= n4) return;
  float4 v = ((const float4*)in)[i];
  ushort4 o;
  o.x = f2b(v.x); o.y = f2b(v.y); o.z = f2b(v.z); o.w = f2b(v.w);
  ((ushort4*)out)[i] = o;
}

// out[c][r] = (c<Cc ? in[r][c] : 0), out has Cp rows. grid(RrN/32, Cp/32), block(32,8)
__global__ __launch_bounds__(256) void tcast(const float* __restrict__ in,
                                             ushort_t* __restrict__ out,
                                             int RrN, int Cc, int Cp) {
  __shared__ float t[32][33];
  int r0 = blockIdx.x * 32, c0 = blockIdx.y * 32;
  int x = threadIdx.x, y = threadIdx.y;
  for (int dy = 0; dy < 32; dy += 8) {
    int r = r0 + y + dy, c = c0 + x;
    t[y + dy][x] = (c < Cc) ? in[(size_t)r * Cc + c] : 0.f;
  }
  __syncthreads();
  for (int dy = 0; dy < 32; dy += 8) {
    int c = c0 + y + dy, r = r0 + x;
    if (c < Cp) out[(size_t)c * RrN + r] = f2b(t[x][y + dy]);
  }
}

// bf16 batched transpose. grid(Cc/64, RrN/64, Z), block(64,8)
__global__ __launch_bounds__(512) void transpose_bf(const ushort_t* __restrict__ in,
                                                    ushort_t* __restrict__ out,
                                                    int RrN, int Cc, long long sIn, long long sOut) {
  __shared__ ushort_t t[64][65];
  int z = blockIdx.z;
  int r0 = blockIdx.y * 64, c0 = blockIdx.x * 64;
  int x = threadIdx.x, y = threadIdx.y;
  const ushort_t* ip = in + (size_t)z * sIn;
  ushort_t* op = out + (size_t)z * sOut;
  for (int dy = 0; dy < 64; dy += 8)
    t[y + dy][x] = ip[(size_t)(r0 + y + dy) * Cc + c0 + x];
  __syncthreads();
  for (int dy = 0; dy < 64; dy += 8)
    op[(size_t)(c0 + y + dy) * RrN + r0 + x] = t[x][y + dy];
}

// normalize role_matrix rows (64 x 1024) -> bf16 row-major rmn (64 x 1024)
__global__ __launch_bounds__(256) void rolenorm(const float* __restrict__ rm,
                                                ushort_t* __restrict__ rmn) {
  int r = blockIdx.x, tid = threadIdx.x;
  float4 v = ((const float4*)(rm + (size_t)r * 1024))[tid];
  float s = v.x * v.x + v.y * v.y + v.z * v.z + v.w * v.w;
#pragma unroll
  for (int m = 1; m < 64; m <<= 1) s += __shfl_xor(s, m);
  __shared__ float red[6];
  if ((tid & 63) == 0) red[tid >> 6] = s;
  __syncthreads();
  if (tid == 0) red[4] = 1.f / fmaxf(sqrtf(red[0] + red[1] + red[2] + red[3]), 1e-12f);
  __syncthreads();
  float inv = red[4];
  ushort4 o;
  o.x = f2b(v.x * inv); o.y = f2b(v.y * inv); o.z = f2b(v.z * inv); o.w = f2b(v.w * inv);
  ((ushort4*)(rmn + (size_t)r * 1024))[tid] = o;
}

// RFnT[f,r] = sum_k FTab[f,k] * rmn[r,k]; f<1280, r<64, out ld 128 (cols 64..127 unused)
__global__ __launch_bounds__(256) void rfn_kernel(const ushort_t* __restrict__ rmn,
                                                  const ushort_t* __restrict__ ftab,
                                                  ushort_t* __restrict__ RFnT) {
  int f = blockIdx.x;
  int t = threadIdx.x;
  int r = t >> 2, part = t & 3;
  const ushort_t* fr = ftab + (size_t)f * 1024 + part * 256;
  const ushort_t* rr = rmn + (size_t)r * 1024 + part * 256;
  float s = 0.f;
#pragma unroll 4
  for (int i = 0; i < 32; i++) {
    s16x8 a = *(const s16x8*)(fr + i * 8);
    s16x8 b = *(const s16x8*)(rr + i * 8);
#pragma unroll
    for (int j = 0; j < 8; j++) s += b2f((ushort_t)a[j]) * b2f((ushort_t)b[j]);
  }
  s += __shfl_xor(s, 1);
  s += __shfl_xor(s, 2);
  if (part == 0) RFnT[(size_t)f * 128 + r] = f2b(s);
}

// scale rows by 1/max(sqrt(sumsq),1e-12): in/out bf16 (rows x 1024), 8 elems/thread
__global__ __launch_bounds__(256) void scale_rows(const ushort_t* __restrict__ in,
                                                  ushort_t* __restrict__ out,
                                                  const float* __restrict__ sumsq) {
  int gid = blockIdx.x * 256 + threadIdx.x;   // NT*128 total
  int row = gid >> 7;
  int c0 = (gid & 127) << 3;
  float inv = 1.f / fmaxf(sqrtf(sumsq[row]), 1e-12f);
  const s16x8* p = (const s16x8*)(in + (size_t)row * 1024 + c0);
  s16x8 v = *p;
  s16x8 o;
#pragma unroll
  for (int i = 0; i < 8; i++) o[i] = (short)f2b(b2f((ushort_t)v[i]) * inv);
  *(s16x8*)(out + (size_t)row * 1024 + c0) = o;
}

// per-batch sum of row norms: ssum[b] += sum over rows of sqrt(sumsq[row])
__global__ __launch_bounds__(256) void surprise_sum(const float* __restrict__ sumsq,
                                                    float* __restrict__ ssum) {
  int row = blockIdx.x * 256 + threadIdx.x;   // NT
  float nrm = sqrtf(sumsq[row]);
#pragma unroll
  for (int m = 1; m < 64; m <<= 1) nrm += __shfl_xor(nrm, m);
  if ((threadIdx.x & 63) == 0) atomicAdd(&ssum[row >> 11], nrm);
}

__global__ void finalize_astro(const float* __restrict__ ssum, const float* __restrict__ astro,
                               const float* __restrict__ ascale, float* __restrict__ tau,
                               float* __restrict__ outTail) {
  int b = threadIdx.x;
  if (b < Bq) {
    float mean = ssum[b] * (1.f / (32.f * 2048.f));  // norm/sqrt(D), averaged over TQ
    float ns = 0.95f * astro[b] + 0.05f * mean;
    tau[b] = fmaxf(1.f + ascale[0] * ns, 0.001f);
    outTail[b] = ns;
  }
}

// softmax over 64 logits per row (logits stride 128), out bf16 (rows x 64)
__global__ __launch_bounds__(256) void softmax64(const float* __restrict__ logits,
                                                 ushort_t* __restrict__ out) {
  int row = blockIdx.x * 4 + (threadIdx.x >> 6);
  int lane = threadIdx.x & 63;
  float x = logits[(size_t)row * 128 + lane];
  float m = x;
#pragma unroll
  for (int s = 1; s < 64; s <<= 1) m = fmaxf(m, __shfl_xor(m, s));
  float e = expf(x - m);
  float sum = e;
#pragma unroll
  for (int s = 1; s < 64; s <<= 1) sum += __shfl_xor(sum, s);
  out[(size_t)row * 64 + lane] = f2b(e / sum);
}

// DFT tables
__global__ __launch_bounds__(256) void gen_ftab(ushort_t* __restrict__ ftab) {
  const float TW = 6.283185307179586f / 1024.f;
  int idx = blockIdx.x * 256 + threadIdx.x;
  int rowf = idx >> 10, k = idx & 1023;
  int f = rowf < FP ? rowf : rowf - FP;
  float v = 0.f;
  if (f <= 512) {
    float th = (float)((f * k) & 1023) * TW;
    float sv, cv; sincosf(th, &sv, &cv);
    v = (rowf < FP) ? cv : -sv;
  }
  ftab[idx] = f2b(v);
}
__global__ __launch_bounds__(256) void gen_itab(ushort_t* __restrict__ itab) {
  const float TW = 6.283185307179586f / 1024.f;
  int idx = blockIdx.x * 256 + threadIdx.x;
  int n = idx / F2;
  int c = idx - n * F2;
  int f = c < FP ? c : c - FP;
  float v = 0.f;
  if (f <= 512) {
    float w = (f == 0 || f == 512) ? (1.f / 1024.f) : (2.f / 1024.f);
    float th = (float)((f * n) & 1023) * TW;
    float sv, cv; sincosf(th, &sv, &cv);
    v = (c < FP) ? w * cv : -w * sv;
  }
  itab[idx] = f2b(v);
}

// pointwise complex product of spectra (bf16), layout [re(640)|im(640)]
__global__ __launch_bounds__(256) void fftmul(const ushort_t* __restrict__ KF,
                                              const ushort_t* __restrict__ RF,
                                              ushort_t* __restrict__ P) {
  int idx = blockIdx.x * 256 + threadIdx.x;   // [0, NT*FP)
  int t = idx / FP;
  int f = idx - t * FP;
  size_t base = (size_t)t * F2;
  float a = b2f(KF[base + f]), b = b2f(KF[base + FP + f]);
  float c = b2f(RF[base + f]), d = b2f(RF[base + FP + f]);
  P[base + f]      = f2b(a * c - b * d);
  P[base + FP + f] = f2b(a * d + b * c);
}

// ---------------------------------------------------------------------------
// workspace layout (bytes)
// ---------------------------------------------------------------------------
static constexpr size_t OFF_RS    = 0;                      // 32 KB rowsum (scores)
static constexpr size_t OFF_SSQQ  = 32768;                  // 32 KB sumsq Q
static constexpr size_t OFF_SSQK  = 65536;                  // 32 KB sumsq K_bound
static constexpr size_t OFF_SSUM  = 98304;                  // 16 B
static constexpr size_t OFF_TAU   = 98320;                  // 16 B
static constexpr size_t OFF_WQT   = 98816;
static constexpr size_t OFF_WKT   = OFF_WQT  + 2097152;
static constexpr size_t OFF_WVT   = OFF_WKT  + 2097152;
static constexpr size_t OFF_WOT   = OFF_WVT  + 2097152;
static constexpr size_t OFF_WR1T  = OFF_WOT  + 2097152;
static constexpr size_t OFF_WR2T  = OFF_WR1T + 1048576;
static constexpr size_t OFF_RMN   = OFF_WR2T + 131072;      // 64x1024 bf16
static constexpr size_t OFF_FTAB  = OFF_RMN  + 131072;      // 1280x1024 bf16
static constexpr size_t OFF_ITAB  = OFF_FTAB + 2621440;     // 1024x1280 bf16
static constexpr size_t OFF_RFNT  = OFF_ITAB + 2621440;     // 1280x128 bf16
static constexpr size_t OFF_R1    = OFF_RFNT + 327680;      // 20 MB  qbf -> KF
static constexpr size_t OFF_R2    = OFF_R1   + 20971520;    // 20 MB  kinb -> RF
static constexpr size_t OFF_R3    = OFF_R2   + 20971520;    // 20 MB  vinb -> Pb
static constexpr size_t OFF_R4    = OFF_R3   + 20971520;    // 16 MB  qraw -> kn
static constexpr size_t OFF_R5    = OFF_R4   + 16777216;    // 16 MB  qn
static constexpr size_t OFF_R6    = OFF_R5   + 16777216;    // 16 MB  kp -> ctx
static constexpr size_t OFF_R7    = OFF_R6   + 16777216;    // 16 MB  vp -> kbraw
static constexpr size_t OFF_R8    = OFF_R7   + 16777216;    // 16 MB  vT
static constexpr size_t OFF_HID   = OFF_R8   + 16777216;    // 8 MB
static constexpr size_t OFF_LOGI  = OFF_HID  + 8388608;     // 4 MB
static constexpr size_t OFF_RW    = OFF_LOGI + 4194304;     // 1 MB
static constexpr size_t OFF_SB    = OFF_RW   + 1048576;     // 32 MB scores
static constexpr size_t WS_NEEDED = OFF_SB   + 33554432;    // ~209.4 MB

static inline void launch_gemm(hipStream_t s, const ushort_t* A, const ushort_t* Bt,
                               float* C, ushort_t* Cbf, const float* bias, const float* tau,
                               float* rowsum, int rsStride, int rsMode,
                               int M, int N, int K, int lda, int ldb, int ldc,
                               long long sA, long long sB, long long sC, int Z, int flags) {
  dim3 g(N / 128, M / 128, Z), b(256);
  gemm_bt<<<g, b, 0, s>>>(A, Bt, C, Cbf, bias, tau, rowsum, rsStride, rsMode,
                          K, lda, ldb, ldc, sA, sB, sC, flags);
}

extern "C" void kernel_launch(void* const* d_in, const int* in_sizes, int n_in,
                              void* d_out, int out_size, void* d_ws, size_t ws_size,
                              hipStream_t stream) {
  (void)in_sizes; (void)n_in; (void)out_size;
  if (ws_size < WS_NEEDED) return;

  const float* q_in  = (const float*)d_in[0];
  const float* k_in  = (const float*)d_in[1];
  const float* v_in  = (const float*)d_in[2];
  const float* astro = (const float*)d_in[3];
  const float* Wq    = (const float*)d_in[4];
  const float* bq    = (const float*)d_in[5];
  const float* Wk    = (const float*)d_in[6];
  const float* bk    = (const float*)d_in[7];
  const float* Wv    = (const float*)d_in[8];
  const float* bv    = (const float*)d_in[9];
  const float* Wo    = (const float*)d_in[10];
  const float* bo    = (const float*)d_in[11];
  const float* roleM = (const float*)d_in[12];
  const float* Wr1   = (const float*)d_in[13];
  const float* br1   = (const float*)d_in[14];
  const float* Wr2   = (const float*)d_in[15];
  const float* ascl  = (const float*)d_in[16];

  char* ws = (char*)d_ws;
  float*    rowsumS = (float*)(ws + OFF_RS);
  float*    ssqQ    = (float*)(ws + OFF_SSQQ);
  float*    ssqK    = (float*)(ws + OFF_SSQK);
  float*    ssum    = (float*)(ws + OFF_SSUM);
  float*    tau     = (float*)(ws + OFF_TAU);
  ushort_t* WqT  = (ushort_t*)(ws + OFF_WQT);
  ushort_t* WkT  = (ushort_t*)(ws + OFF_WKT);
  ushort_t* WvT  = (ushort_t*)(ws + OFF_WVT);
  ushort_t* WoT  = (ushort_t*)(ws + OFF_WOT);
  ushort_t* Wr1T = (ushort_t*)(ws + OFF_WR1T);
  ushort_t* Wr2T = (ushort_t*)(ws + OFF_WR2T);
  ushort_t* rmn  = (ushort_t*)(ws + OFF_RMN);
  ushort_t* FTab = (ushort_t*)(ws + OFF_FTAB);
  ushort_t* ITab = (ushort_t*)(ws + OFF_ITAB);
  ushort_t* RFnT = (ushort_t*)(ws + OFF_RFNT);
  ushort_t* qbf  = (ushort_t*)(ws + OFF_R1);
  ushort_t* KF   = (ushort_t*)(ws + OFF_R1);
  ushort_t* kinb = (ushort_t*)(ws + OFF_R2);
  ushort_t* RF   = (ushort_t*)(ws + OFF_R2);
  ushort_t* vinb = (ushort_t*)(ws + OFF_R3);
  ushort_t* Pb   = (ushort_t*)(ws + OFF_R3);
  ushort_t* qraw = (ushort_t*)(ws + OFF_R4);
  ushort_t* kn   = (ushort_t*)(ws + OFF_R4);
  ushort_t* qn   = (ushort_t*)(ws + OFF_R5);
  ushort_t* kp   = (ushort_t*)(ws + OFF_R6);
  ushort_t* ctx  = (ushort_t*)(ws + OFF_R6);
  ushort_t* vp   = (ushort_t*)(ws + OFF_R7);
  ushort_t* kbraw= (ushort_t*)(ws + OFF_R7);
  ushort_t* vT   = (ushort_t*)(ws + OFF_R8);
  ushort_t* hid  = (ushort_t*)(ws + OFF_HID);
  float*    logi = (float*)(ws + OFF_LOGI);
  ushort_t* rw   = (ushort_t*)(ws + OFF_RW);
  ushort_t* Sb   = (ushort_t*)(ws + OFF_SB);
  float*    out  = (float*)d_out;

  // 0. zero accumulators (rowsumS + ssqQ + ssqK + ssum)
  hipMemsetAsync(ws, 0, 98320, stream);

  // 1. weight prep + tables
  tcast<<<dim3(32, 32), dim3(32, 8), 0, stream>>>(Wq, WqT, 1024, 1024, 1024);
  tcast<<<dim3(32, 32), dim3(32, 8), 0, stream>>>(Wk, WkT, 1024, 1024, 1024);
  tcast<<<dim3(32, 32), dim3(32, 8), 0, stream>>>(Wv, WvT, 1024, 1024, 1024);
  tcast<<<dim3(32, 32), dim3(32, 8), 0, stream>>>(Wo, WoT, 1024, 1024, 1024);
  tcast<<<dim3(32, 16), dim3(32, 8), 0, stream>>>(Wr1, Wr1T, 1024, 512, 512);
  tcast<<<dim3(16, 4),  dim3(32, 8), 0, stream>>>(Wr2, Wr2T, 512, 64, 128);
  rolenorm<<<64, 256, 0, stream>>>(roleM, rmn);
  gen_ftab<<<(F2 * 1024) / 256, 256, 0, stream>>>(FTab);
  gen_itab<<<(1024 * F2) / 256, 256, 0, stream>>>(ITab);
  rfn_kernel<<<F2, 256, 0, stream>>>(rmn, FTab, RFnT);

  // 2. Q path: cast -> proj(+sumsq) -> scale -> surprise -> tau
  castbf<<<8192, 256, 0, stream>>>(q_in, qbf, NT * Dd / 4);
  launch_gemm(stream, qbf, WqT, nullptr, qraw, bq, nullptr, ssqQ, 0, 2,
              NT, Dd, Dd, Dd, Dd, Dd, 0, 0, 0, 1, 0);
  scale_rows<<<NT / 2, 256, 0, stream>>>(qraw, qn, ssqQ);
  surprise_sum<<<NT / 256, 256, 0, stream>>>(ssqQ, ssum);
  finalize_astro<<<1, 64, 0, stream>>>(ssum, astro, ascl, tau, out + (size_t)NT * Dd);

  // 3. K path: cast -> proj
  castbf<<<8192, 256, 0, stream>>>(k_in, kinb, NT * Dd / 4);
  launch_gemm(stream, kinb, WkT, nullptr, kp, bk, nullptr, nullptr, 0, 0,
              NT, Dd, Dd, Dd, Dd, Dd, 0, 0, 0, 1, 0);

  // 4. V path: cast -> proj -> transpose
  castbf<<<8192, 256, 0, stream>>>(v_in, vinb, NT * Dd / 4);
  launch_gemm(stream, vinb, WvT, nullptr, vp, bv, nullptr, nullptr, 0, 0,
              NT, Dd, Dd, Dd, Dd, Dd, 0, 0, 0, 1, 0);
  transpose_bf<<<dim3(16, 32, Bq), dim3(64, 8), 0, stream>>>(
      vp, vT, Tq, Dd, (long long)Tq * Dd, (long long)Dd * Tq);

  // 5. role path: MLP -> softmax -> spectrum via RFnT
  launch_gemm(stream, kp, Wr1T, nullptr, hid, br1, nullptr, nullptr, 0, 0,
              NT, Hh, Dd, Dd, Dd, Hh, 0, 0, 0, 1, 1 /*relu*/);
  launch_gemm(stream, hid, Wr2T, logi, nullptr, nullptr, nullptr, nullptr, 0, 0,
              NT, 128, Hh, Hh, Hh, 128, 0, 0, 0, 1, 0);
  softmax64<<<NT / 4, 256, 0, stream>>>(logi, rw);

  // 6. binding: KF = kp @ FTab^T ; RF = rw @ RFnT^T ; pointwise ; inverse(+sumsq)
  launch_gemm(stream, kp, FTab, nullptr, KF, nullptr, nullptr, nullptr, 0, 0,
              NT, F2, Dd, Dd, Dd, F2, 0, 0, 0, 1, 0);
  launch_gemm(stream, rw, RFnT, nullptr, RF, nullptr, nullptr, nullptr, 0, 0,
              NT, F2, Rr_, Rr_, 128, F2, 0, 0, 0, 1, 0);
  fftmul<<<(NT * FP) / 256, 256, 0, stream>>>(KF, RF, Pb);
  launch_gemm(stream, Pb, ITab, nullptr, kbraw, nullptr, nullptr, ssqK, 0, 2,
              NT, Dd, F2, F2, F2, Dd, 0, 0, 0, 1, 0);
  scale_rows<<<NT / 2, 256, 0, stream>>>(kbraw, kn, ssqK);

  // 7. attention: scores (Epanechnikov, rowsum) -> context (divide by rowsum)
  launch_gemm(stream, qn, kn, nullptr, Sb, nullptr, tau, rowsumS, Tq, 1,
              Tq, Tq, Dd, Dd, Dd, Tq,
              (long long)Tq * Dd, (long long)Tq * Dd, (long long)Tq * Tq, Bq, 0);
  launch_gemm(stream, Sb, vT, nullptr, ctx, nullptr, nullptr, rowsumS, Tq, 3,
              Tq, Dd, Tq, Tq, Tq, Dd,
              (long long)Tq * Tq, (long long)Dd * Tq, (long long)Tq * Dd, Bq, 0);

  // 8. output projection -> d_out
  launch_gemm(stream, ctx, WoT, out, nullptr, bo, nullptr, nullptr, 0, 0,
              NT, Dd, Dd, Dd, Dd, Dd, 0, 0, 0, 1, 0);
}

// Round 3
// 676.987 us; speedup vs baseline: 1.2850x; 1.1434x over previous
//
#include <hip/hip_runtime.h>
#include <stdint.h>

// ---------------------------------------------------------------------------
// AstroSymbolicEpisodicLayer  (B=4, TQ=TK=2048, D=1024, R=64, H=512)
// R3: LDS bank-conflict swizzle in GEMM, norm-folding epilogues, direct V^T
// GEMM, packed 1024-wide rfft spectrum.
// ---------------------------------------------------------------------------

#define Bq 4
#define Tq 2048
#define Dd 1024
#define NT 8192      // B*T
#define Hh 512
#define Rr_ 64
#define FQ 1024      // packed rfft spectrum width: re(0..512) | im(1..511)

typedef unsigned short ushort_t;
typedef short s16x8 __attribute__((ext_vector_type(8)));
typedef float floatx4 __attribute__((ext_vector_type(4)));

__device__ __forceinline__ float b2f(ushort_t s) {
  unsigned u = (unsigned)s << 16;
  return __builtin_bit_cast(float, u);
}
__device__ __forceinline__ ushort_t f2b(float f) {
  unsigned u = __builtin_bit_cast(unsigned, f);
  unsigned r = (u + 0x7fffu + ((u >> 16) & 1u)) >> 16;
  return (ushort_t)r;
}

__device__ __forceinline__ void load_lds16(const void* g, void* l) {
  __builtin_amdgcn_global_load_lds((__attribute__((address_space(1))) void*)(g),
                                   (__attribute__((address_space(3))) void*)(l),
                                   16, 0, 0);
}

// ---------------------------------------------------------------------------
// GEMM: C[M,N] = A[M,K] @ Bt[N,K]^T, tile 128x128, 4 waves, bank-swizzled LDS.
// Epilogue: v = acc (+bias_col[col]) (+bias_row[row]); v *= rmul[row]*cmul[col];
// relu (flags&1); Epanechnikov if tau; rsMode 1/2: atomic rowsum of v / v^2.
// LDS swizzle: chunk c of row r stored at physical chunk (c + ((r&15)>>1)) & 3.
// Makes fragment ds_read_b128 conflict-free (2-way only); staging lane fetches
// the inverse-permuted global chunk since global_load_lds dest is lane-fixed.
// ---------------------------------------------------------------------------
__global__ __launch_bounds__(256) void gemm_bt(
    const ushort_t* __restrict__ A, const ushort_t* __restrict__ Bt,
    float* __restrict__ C, ushort_t* __restrict__ Cbf,
    const float* __restrict__ bias_col, const float* __restrict__ bias_row,
    const float* __restrict__ rmul, int rmulStride,
    const float* __restrict__ cmul, int cmulStride,
    const float* __restrict__ tau,
    float* __restrict__ rowsum, int rsStride, int rsMode,
    int K, int lda, int ldb, int ldc,
    long long sA, long long sB, long long sC, int flags)
{
  __shared__ __align__(16) ushort_t As[128 * 32];
  __shared__ __align__(16) ushort_t Bs[128 * 32];

  const int bz   = blockIdx.z;
  const ushort_t* Ab = A + (size_t)bz * sA;
  const ushort_t* Bb = Bt + (size_t)bz * sB;
  const int tm   = blockIdx.y * 128;
  const int tn   = blockIdx.x * 128;
  const int tid  = threadIdx.x;
  const int wave = tid >> 6;
  const int lane = tid & 63;
  const int wm   = (wave & 1) << 6;
  const int wn   = (wave >> 1) << 6;
  // staging: lane -> (row sr, physical chunk cp); fetch global chunk cg
  const int sr   = lane >> 2;
  const int cp   = lane & 3;
  const int sc   = (((cp - (sr >> 1)) & 3) << 3);   // global elem offset
  // fragment read: row fr, global chunk lane>>4 -> physical chunk
  const int fr   = lane & 15;
  const int fk   = ((((lane >> 4) + (fr >> 1)) & 3) << 3);

  floatx4 acc[4][4] = {};

  for (int k0 = 0; k0 < K; k0 += 32) {
    {
      const ushort_t* gA0 = Ab + (size_t)(tm + wave * 16 + sr) * lda + (k0 + sc);
      const ushort_t* gA1 = gA0 + (size_t)64 * lda;
      char* lA = (char*)As + wave * 1024;
      load_lds16(gA0, lA);
      load_lds16(gA1, lA + 4096);
      const ushort_t* gB0 = Bb + (size_t)(tn + wave * 16 + sr) * ldb + (k0 + sc);
      const ushort_t* gB1 = gB0 + (size_t)64 * ldb;
      char* lB = (char*)Bs + wave * 1024;
      load_lds16(gB0, lB);
      load_lds16(gB1, lB + 4096);
    }
    __syncthreads();
    s16x8 af[4], bfv[4];
#pragma unroll
    for (int i = 0; i < 4; i++)
      af[i] = *(const s16x8*)&As[(wm + i * 16 + fr) * 32 + fk];
#pragma unroll
    for (int j = 0; j < 4; j++)
      bfv[j] = *(const s16x8*)&Bs[(wn + j * 16 + fr) * 32 + fk];
#pragma unroll
    for (int i = 0; i < 4; i++)
#pragma unroll
      for (int j = 0; j < 4; j++)
        acc[i][j] = __builtin_amdgcn_mfma_f32_16x16x32_bf16(af[i], bfv[j], acc[i][j], 0, 0, 0);
    __syncthreads();
  }

  // ---- epilogue ----
  const float tv = tau ? tau[bz] : 0.f;
  float*   Cp  = C   ? C   + (size_t)bz * sC : nullptr;
  ushort_t* Cb = Cbf ? Cbf + (size_t)bz * sC : nullptr;
  float bcv[4], cmv[4];
#pragma unroll
  for (int j = 0; j < 4; j++) {
    const int col = tn + wn + j * 16 + (lane & 15);
    bcv[j] = bias_col ? bias_col[col] : 0.f;
    cmv[j] = cmul ? cmul[(size_t)bz * cmulStride + col] : 1.f;
  }
#pragma unroll
  for (int i = 0; i < 4; i++) {
#pragma unroll
    for (int r = 0; r < 4; r++) {
      const int row = tm + wm + i * 16 + (lane >> 4) * 4 + r;
      const float rm = rmul ? rmul[(size_t)bz * rmulStride + row] : 1.f;
      const float br = bias_row ? bias_row[row] : 0.f;
      float rsum = 0.f;
#pragma unroll
      for (int j = 0; j < 4; j++) {
        const int col = tn + wn + j * 16 + (lane & 15);
        float v = acc[i][j][r] + bcv[j] + br;
        v *= rm * cmv[j];
        if (flags & 1) v = fmaxf(v, 0.f);
        if (tau) { float d = 1.0f - v; v = fmaxf(1.0f - tv * 0.25f * d * d, 0.f); }
        rsum += (rsMode == 2) ? v * v : v;
        if (Cp) Cp[(size_t)row * ldc + col] = v;
        if (Cb) Cb[(size_t)row * ldc + col] = f2b(v);
      }
      if (rsMode == 1 || rsMode == 2) {
        rsum += __shfl_xor(rsum, 1);
        rsum += __shfl_xor(rsum, 2);
        rsum += __shfl_xor(rsum, 4);
        rsum += __shfl_xor(rsum, 8);
        if ((lane & 15) == 0)
          atomicAdd(&rowsum[(size_t)bz * rsStride + row], rsum);
      }
    }
  }
}

// ---------------------------------------------------------------------------
// small kernels
// ---------------------------------------------------------------------------
__global__ __launch_bounds__(256) void castbf(const float* __restrict__ in,
                                              ushort_t* __restrict__ out, int n4) {
  int i = blockIdx.x * 256 + threadIdx.x;
  if (i >= n4) return;
  float4 v = ((const float4*)in)[i];
  ushort4 o;
  o.x = f2b(v.x); o.y = f2b(v.y); o.z = f2b(v.z); o.w = f2b(v.w);
  ((ushort4*)out)[i] = o;
}

struct TC4 { const float* in[4]; ushort_t* out[4]; };
// 4x fused 1024x1024 transpose+cast. grid(32,32,4), block(32,8)
__global__ __launch_bounds__(256) void tcast4(TC4 p) {
  __shared__ float t[32][33];
  int z = blockIdx.z;
  const float* in = p.in[z];
  ushort_t* out = p.out[z];
  int r0 = blockIdx.x * 32, c0 = blockIdx.y * 32;
  int x = threadIdx.x, y = threadIdx.y;
  for (int dy = 0; dy < 32; dy += 8)
    t[y + dy][x] = in[(size_t)(r0 + y + dy) * 1024 + c0 + x];
  __syncthreads();
  for (int dy = 0; dy < 32; dy += 8)
    out[(size_t)(c0 + y + dy) * 1024 + r0 + x] = f2b(t[x][y + dy]);
}

// out[c][r] = (c<Cc ? in[r][c] : 0), out has Cp rows. grid(RrN/32, Cp/32), block(32,8)
__global__ __launch_bounds__(256) void tcast(const float* __restrict__ in,
                                             ushort_t* __restrict__ out,
                                             int RrN, int Cc, int Cp) {
  __shared__ float t[32][33];
  int r0 = blockIdx.x * 32, c0 = blockIdx.y * 32;
  int x = threadIdx.x, y = threadIdx.y;
  for (int dy = 0; dy < 32; dy += 8) {
    int r = r0 + y + dy, c = c0 + x;
    t[y + dy][x] = (c < Cc) ? in[(size_t)r * Cc + c] : 0.f;
  }
  __syncthreads();
  for (int dy = 0; dy < 32; dy += 8) {
    int c = c0 + y + dy, r = r0 + x;
    if (c < Cp) out[(size_t)c * RrN + r] = f2b(t[x][y + dy]);
  }
}

// normalize role_matrix rows (64 x 1024) -> bf16 row-major rmn (64 x 1024)
__global__ __launch_bounds__(256) void rolenorm(const float* __restrict__ rm,
                                                ushort_t* __restrict__ rmn) {
  int r = blockIdx.x, tid = threadIdx.x;
  float4 v = ((const float4*)(rm + (size_t)r * 1024))[tid];
  float s = v.x * v.x + v.y * v.y + v.z * v.z + v.w * v.w;
#pragma unroll
  for (int m = 1; m < 64; m <<= 1) s += __shfl_xor(s, m);
  __shared__ float red[6];
  if ((tid & 63) == 0) red[tid >> 6] = s;
  __syncthreads();
  if (tid == 0) red[4] = 1.f / fmaxf(sqrtf(red[0] + red[1] + red[2] + red[3]), 1e-12f);
  __syncthreads();
  float inv = red[4];
  ushort4 o;
  o.x = f2b(v.x * inv); o.y = f2b(v.y * inv); o.z = f2b(v.z * inv); o.w = f2b(v.w * inv);
  ((ushort4*)(rmn + (size_t)r * 1024))[tid] = o;
}

// RFnT[j,r] = sum_k FTab[j,k] * rmn[r,k]; j<1024, r<64, out ld 128
__global__ __launch_bounds__(256) void rfn_kernel(const ushort_t* __restrict__ rmn,
                                                  const ushort_t* __restrict__ ftab,
                                                  ushort_t* __restrict__ RFnT) {
  int f = blockIdx.x;
  int t = threadIdx.x;
  int r = t >> 2, part = t & 3;
  const ushort_t* fr = ftab + (size_t)f * 1024 + part * 256;
  const ushort_t* rr = rmn + (size_t)r * 1024 + part * 256;
  float s = 0.f;
#pragma unroll 4
  for (int i = 0; i < 32; i++) {
    s16x8 a = *(const s16x8*)(fr + i * 8);
    s16x8 b = *(const s16x8*)(rr + i * 8);
#pragma unroll
    for (int j = 0; j < 8; j++) s += b2f((ushort_t)a[j]) * b2f((ushort_t)b[j]);
  }
  s += __shfl_xor(s, 1);
  s += __shfl_xor(s, 2);
  if (part == 0) RFnT[(size_t)f * 128 + r] = f2b(s);
}

// invQ = 1/max(||row||,eps); ssum[b] += ||row||  (NT threads)
__global__ __launch_bounds__(256) void invnorm_surprise(const float* __restrict__ ssq,
                                                        float* __restrict__ invn,
                                                        float* __restrict__ ssum) {
  int row = blockIdx.x * 256 + threadIdx.x;
  float nrm = sqrtf(ssq[row]);
  invn[row] = 1.f / fmaxf(nrm, 1e-12f);
  float t = nrm;
#pragma unroll
  for (int m = 1; m < 64; m <<= 1) t += __shfl_xor(t, m);
  if ((threadIdx.x & 63) == 0) atomicAdd(&ssum[row >> 11], t);
}

// invn = 1/max(sqrt(ssq),1e-12)
__global__ __launch_bounds__(256) void invnorm(const float* __restrict__ ssq,
                                               float* __restrict__ invn) {
  int row = blockIdx.x * 256 + threadIdx.x;
  invn[row] = 1.f / fmaxf(sqrtf(ssq[row]), 1e-12f);
}

// invRS = 1/max(rowsum,1e-9)
__global__ __launch_bounds__(256) void invrowsum(const float* __restrict__ rs,
                                                 float* __restrict__ inv) {
  int row = blockIdx.x * 256 + threadIdx.x;
  inv[row] = 1.f / fmaxf(rs[row], 1e-9f);
}

__global__ void finalize_astro(const float* __restrict__ ssum, const float* __restrict__ astro,
                               const float* __restrict__ ascale, float* __restrict__ tau,
                               float* __restrict__ outTail) {
  int b = threadIdx.x;
  if (b < Bq) {
    float mean = ssum[b] * (1.f / (32.f * 2048.f));  // norm/sqrt(D), averaged over TQ
    float ns = 0.95f * astro[b] + 0.05f * mean;
    tau[b] = fmaxf(1.f + ascale[0] * ns, 0.001f);
    outTail[b] = ns;
  }
}

// softmax over 64 logits per row (logits stride 128), out bf16 (rows x 64)
__global__ __launch_bounds__(256) void softmax64(const float* __restrict__ logits,
                                                 ushort_t* __restrict__ out) {
  int row = blockIdx.x * 4 + (threadIdx.x >> 6);
  int lane = threadIdx.x & 63;
  float x = logits[(size_t)row * 128 + lane];
  float m = x;
#pragma unroll
  for (int s = 1; s < 64; s <<= 1) m = fmaxf(m, __shfl_xor(m, s));
  float e = expf(x - m);
  float sum = e;
#pragma unroll
  for (int s = 1; s < 64; s <<= 1) sum += __shfl_xor(sum, s);
  out[(size_t)row * 64 + lane] = f2b(e / sum);
}

// packed forward DFT table (1024 rows j x 1024 cols k):
// j<=512: cos(2pi j k/1024); j>512: f=j-512, -sin(2pi f k/1024)  [= Im coeff]
__global__ __launch_bounds__(256) void gen_ftab(ushort_t* __restrict__ ftab) {
  const float TW = 6.283185307179586f / 1024.f;
  int idx = blockIdx.x * 256 + threadIdx.x;
  int j = idx >> 10, k = idx & 1023;
  int f = j <= 512 ? j : j - 512;
  float th = (float)((f * k) & 1023) * TW;
  float sv, cv; sincosf(th, &sv, &cv);
  ftab[idx] = f2b(j <= 512 ? cv : -sv);
}
// packed inverse table (1024 rows n x 1024 cols j):
// j<=512: w_j cos(2pi j n/1024), w={1,..2..,1}/1024; j>512: -(2/1024) sin(2pi f n/1024)
__global__ __launch_bounds__(256) void gen_itab(ushort_t* __restrict__ itab) {
  const float TW = 6.283185307179586f / 1024.f;
  int idx = blockIdx.x * 256 + threadIdx.x;
  int n = idx >> 10, j = idx & 1023;
  float v;
  if (j <= 512) {
    float w = (j == 0 || j == 512) ? (1.f / 1024.f) : (2.f / 1024.f);
    float th = (float)((j * n) & 1023) * TW;
    float sv, cv; sincosf(th, &sv, &cv);
    v = w * cv;
  } else {
    int f = j - 512;
    float th = (float)((f * n) & 1023) * TW;
    float sv, cv; sincosf(th, &sv, &cv);
    v = -(2.f / 1024.f) * sv;
  }
  itab[idx] = f2b(v);
}

// packed pointwise complex product: per token, cols [0..512]=re, [513..1023]=im(1..511)
__global__ __launch_bounds__(256) void fftmul(const ushort_t* __restrict__ KF,
                                              const ushort_t* __restrict__ RF,
                                              ushort_t* __restrict__ P) {
  int idx = blockIdx.x * 256 + threadIdx.x;   // [0, NT*512)
  int t = idx >> 9;
  int j = idx & 511;
  size_t base = (size_t)t * FQ;
  if (j == 0) {
    P[base]       = f2b(b2f(KF[base]) * b2f(RF[base]));
    P[base + 512] = f2b(b2f(KF[base + 512]) * b2f(RF[base + 512]));
  } else {
    float a = b2f(KF[base + j]), b = b2f(KF[base + 512 + j]);
    float c = b2f(RF[base + j]), d = b2f(RF[base + 512 + j]);
    P[base + j]       = f2b(a * c - b * d);
    P[base + 512 + j] = f2b(a * d + b * c);
  }
}

// ---------------------------------------------------------------------------
// workspace layout (bytes, 256-aligned)
// ---------------------------------------------------------------------------
static constexpr size_t OFF_RS    = 0;                      // 32 KB rowsum (scores)
static constexpr size_t OFF_SSQQ  = 32768;
static constexpr size_t OFF_SSQK  = 65536;
static constexpr size_t OFF_INVQ  = 98304;
static constexpr size_t OFF_INVK  = 131072;
static constexpr size_t OFF_INVRS = 163840;
static constexpr size_t OFF_SSUM  = 196608;                 // 16 B
static constexpr size_t OFF_TAU   = 196864;                 // 16 B
static constexpr size_t OFF_WQT   = 197120;
static constexpr size_t OFF_WKT   = OFF_WQT  + 2097152;
static constexpr size_t OFF_WVT   = OFF_WKT  + 2097152;
static constexpr size_t OFF_WOT   = OFF_WVT  + 2097152;
static constexpr size_t OFF_WR1T  = OFF_WOT  + 2097152;
static constexpr size_t OFF_WR2T  = OFF_WR1T + 1048576;
static constexpr size_t OFF_RMN   = OFF_WR2T + 131072;      // 64x1024 bf16
static constexpr size_t OFF_FTAB  = OFF_RMN  + 131072;      // 1024x1024 bf16
static constexpr size_t OFF_ITAB  = OFF_FTAB + 2097152;
static constexpr size_t OFF_RFNT  = OFF_ITAB + 2097152;     // 1024x128 bf16
static constexpr size_t OFF_B1    = OFF_RFNT + 262144;      // qbf -> KF   (16MB)
static constexpr size_t OFF_B2    = OFF_B1   + 16777216;    // kinb -> RF  (16MB)
static constexpr size_t OFF_B3    = OFF_B2   + 16777216;    // vinb -> Pb  (16MB)
static constexpr size_t OFF_B4    = OFF_B3   + 16777216;    // qraw        (16MB)
static constexpr size_t OFF_B5    = OFF_B4   + 16777216;    // kbraw       (16MB)
static constexpr size_t OFF_B6    = OFF_B5   + 16777216;    // kp -> ctx   (16MB)
static constexpr size_t OFF_B7    = OFF_B6   + 16777216;    // vT          (16MB)
static constexpr size_t OFF_HID   = OFF_B7   + 16777216;    // 8MB
static constexpr size_t OFF_LOGI  = OFF_HID  + 8388608;     // 4MB
static constexpr size_t OFF_RW    = OFF_LOGI + 4194304;     // 1MB
static constexpr size_t OFF_SB    = OFF_RW   + 1048576;     // 32MB scores
static constexpr size_t WS_NEEDED = OFF_SB   + 33554432;    // ~179 MB

static inline void launch_gemm(hipStream_t s, const ushort_t* A, const ushort_t* Bt,
                               float* Cf, ushort_t* Cb,
                               const float* bias_col, const float* bias_row,
                               const float* rmul, int rmulStride,
                               const float* cmul, int cmulStride,
                               const float* tau, float* rowsum, int rsStride, int rsMode,
                               int M, int N, int K, int lda, int ldb, int ldc,
                               long long sA, long long sB, long long sC, int Z, int flags) {
  dim3 g(N / 128, M / 128, Z), b(256);
  gemm_bt<<<g, b, 0, s>>>(A, Bt, Cf, Cb, bias_col, bias_row, rmul, rmulStride,
                          cmul, cmulStride, tau, rowsum, rsStride, rsMode,
                          K, lda, ldb, ldc, sA, sB, sC, flags);
}

extern "C" void kernel_launch(void* const* d_in, const int* in_sizes, int n_in,
                              void* d_out, int out_size, void* d_ws, size_t ws_size,
                              hipStream_t stream) {
  (void)in_sizes; (void)n_in; (void)out_size;
  if (ws_size < WS_NEEDED) return;

  const float* q_in  = (const float*)d_in[0];
  const float* k_in  = (const float*)d_in[1];
  const float* v_in  = (const float*)d_in[2];
  const float* astro = (const float*)d_in[3];
  const float* Wq    = (const float*)d_in[4];
  const float* bq    = (const float*)d_in[5];
  const float* Wk    = (const float*)d_in[6];
  const float* bk    = (const float*)d_in[7];
  const float* Wv    = (const float*)d_in[8];
  const float* bv    = (const float*)d_in[9];
  const float* Wo    = (const float*)d_in[10];
  const float* bo    = (const float*)d_in[11];
  const float* roleM = (const float*)d_in[12];
  const float* Wr1   = (const float*)d_in[13];
  const float* br1   = (const float*)d_in[14];
  const float* Wr2   = (const float*)d_in[15];
  const float* ascl  = (const float*)d_in[16];

  char* ws = (char*)d_ws;
  float*    rowsumS = (float*)(ws + OFF_RS);
  float*    ssqQ    = (float*)(ws + OFF_SSQQ);
  float*    ssqK    = (float*)(ws + OFF_SSQK);
  float*    invQ    = (float*)(ws + OFF_INVQ);
  float*    invK    = (float*)(ws + OFF_INVK);
  float*    invRS   = (float*)(ws + OFF_INVRS);
  float*    ssum    = (float*)(ws + OFF_SSUM);
  float*    tau     = (float*)(ws + OFF_TAU);
  ushort_t* WqT  = (ushort_t*)(ws + OFF_WQT);
  ushort_t* WkT  = (ushort_t*)(ws + OFF_WKT);
  ushort_t* WvT  = (ushort_t*)(ws + OFF_WVT);
  ushort_t* WoT  = (ushort_t*)(ws + OFF_WOT);
  ushort_t* Wr1T = (ushort_t*)(ws + OFF_WR1T);
  ushort_t* Wr2T = (ushort_t*)(ws + OFF_WR2T);
  ushort_t* rmn  = (ushort_t*)(ws + OFF_RMN);
  ushort_t* FTab = (ushort_t*)(ws + OFF_FTAB);
  ushort_t* ITab = (ushort_t*)(ws + OFF_ITAB);
  ushort_t* RFnT = (ushort_t*)(ws + OFF_RFNT);
  ushort_t* qbf  = (ushort_t*)(ws + OFF_B1);
  ushort_t* KF   = (ushort_t*)(ws + OFF_B1);
  ushort_t* kinb = (ushort_t*)(ws + OFF_B2);
  ushort_t* RF   = (ushort_t*)(ws + OFF_B2);
  ushort_t* vinb = (ushort_t*)(ws + OFF_B3);
  ushort_t* Pb   = (ushort_t*)(ws + OFF_B3);
  ushort_t* qraw = (ushort_t*)(ws + OFF_B4);
  ushort_t* kbraw= (ushort_t*)(ws + OFF_B5);
  ushort_t* kp   = (ushort_t*)(ws + OFF_B6);
  ushort_t* ctx  = (ushort_t*)(ws + OFF_B6);
  ushort_t* vT   = (ushort_t*)(ws + OFF_B7);
  ushort_t* hid  = (ushort_t*)(ws + OFF_HID);
  float*    logi = (float*)(ws + OFF_LOGI);
  ushort_t* rw   = (ushort_t*)(ws + OFF_RW);
  ushort_t* Sb   = (ushort_t*)(ws + OFF_SB);
  float*    out  = (float*)d_out;

  // 0. zero accumulators (rowsumS..ssum)
  hipMemsetAsync(ws, 0, OFF_SSUM + 256, stream);

  // 1. weight prep + tables
  TC4 tc4;
  tc4.in[0] = Wq; tc4.in[1] = Wk; tc4.in[2] = Wv; tc4.in[3] = Wo;
  tc4.out[0] = WqT; tc4.out[1] = WkT; tc4.out[2] = WvT; tc4.out[3] = WoT;
  tcast4<<<dim3(32, 32, 4), dim3(32, 8), 0, stream>>>(tc4);
  tcast<<<dim3(32, 16), dim3(32, 8), 0, stream>>>(Wr1, Wr1T, 1024, 512, 512);
  tcast<<<dim3(16, 4),  dim3(32, 8), 0, stream>>>(Wr2, Wr2T, 512, 64, 128);
  rolenorm<<<64, 256, 0, stream>>>(roleM, rmn);
  gen_ftab<<<(FQ * 1024) / 256, 256, 0, stream>>>(FTab);
  gen_itab<<<(1024 * FQ) / 256, 256, 0, stream>>>(ITab);
  rfn_kernel<<<FQ, 256, 0, stream>>>(rmn, FTab, RFnT);

  // 2. Q path: cast -> proj(+sumsq) -> invnorm+surprise -> tau
  castbf<<<8192, 256, 0, stream>>>(q_in, qbf, NT * Dd / 4);
  launch_gemm(stream, qbf, WqT, nullptr, qraw, bq, nullptr,
              nullptr, 0, nullptr, 0, nullptr, ssqQ, 0, 2,
              NT, Dd, Dd, Dd, Dd, Dd, 0, 0, 0, 1, 0);
  invnorm_surprise<<<NT / 256, 256, 0, stream>>>(ssqQ, invQ, ssum);
  finalize_astro<<<1, 64, 0, stream>>>(ssum, astro, ascl, tau, out + (size_t)NT * Dd);

  // 3. K path: cast -> proj
  castbf<<<8192, 256, 0, stream>>>(k_in, kinb, NT * Dd / 4);
  launch_gemm(stream, kinb, WkT, nullptr, kp, bk, nullptr,
              nullptr, 0, nullptr, 0, nullptr, nullptr, 0, 0,
              NT, Dd, Dd, Dd, Dd, Dd, 0, 0, 0, 1, 0);

  // 4. V path: cast -> direct V^T GEMM (row-bias)
  castbf<<<8192, 256, 0, stream>>>(v_in, vinb, NT * Dd / 4);
  launch_gemm(stream, WvT, vinb, nullptr, vT, nullptr, bv,
              nullptr, 0, nullptr, 0, nullptr, nullptr, 0, 0,
              Dd, NT, Dd, Dd, Dd, NT, 0, 0, 0, 1, 0);

  // 5. role path: MLP -> softmax
  launch_gemm(stream, kp, Wr1T, nullptr, hid, br1, nullptr,
              nullptr, 0, nullptr, 0, nullptr, nullptr, 0, 0,
              NT, Hh, Dd, Dd, Dd, Hh, 0, 0, 0, 1, 1 /*relu*/);
  launch_gemm(stream, hid, Wr2T, logi, nullptr, nullptr, nullptr,
              nullptr, 0, nullptr, 0, nullptr, nullptr, 0, 0,
              NT, 128, Hh, Hh, Hh, 128, 0, 0, 0, 1, 0);
  softmax64<<<NT / 4, 256, 0, stream>>>(logi, rw);

  // 6. binding: KF = kp@FTab^T ; RF = rw@RFnT^T ; pointwise ; inverse(+sumsq)
  launch_gemm(stream, kp, FTab, nullptr, KF, nullptr, nullptr,
              nullptr, 0, nullptr, 0, nullptr, nullptr, 0, 0,
              NT, FQ, Dd, Dd, Dd, FQ, 0, 0, 0, 1, 0);
  launch_gemm(stream, rw, RFnT, nullptr, RF, nullptr, nullptr,
              nullptr, 0, nullptr, 0, nullptr, nullptr, 0, 0,
              NT, FQ, Rr_, Rr_, 128, FQ, 0, 0, 0, 1, 0);
  fftmul<<<(NT * 512) / 256, 256, 0, stream>>>(KF, RF, Pb);
  launch_gemm(stream, Pb, ITab, nullptr, kbraw, nullptr, nullptr,
              nullptr, 0, nullptr, 0, nullptr, ssqK, 0, 2,
              NT, Dd, FQ, FQ, FQ, Dd, 0, 0, 0, 1, 0);
  invnorm<<<NT / 256, 256, 0, stream>>>(ssqK, invK);

  // 7. attention: scores (norm-folded Epanechnikov + rowsum) -> context (x invRS)
  launch_gemm(stream, qraw, kbraw, nullptr, Sb, nullptr, nullptr,
              invQ, Tq, invK, Tq, tau, rowsumS, Tq, 1,
              Tq, Tq, Dd, Dd, Dd, Tq,
              (long long)Tq * Dd, (long long)Tq * Dd, (long long)Tq * Tq, Bq, 0);
  invrowsum<<<NT / 256, 256, 0, stream>>>(rowsumS, invRS);
  launch_gemm(stream, Sb, vT, nullptr, ctx, nullptr, nullptr,
              invRS, Tq, nullptr, 0, nullptr, nullptr, 0, 0,
              Tq, Dd, Tq, Tq, NT, Dd,
              (long long)Tq * Tq, (long long)Tq, (long long)Tq * Dd, Bq, 0);

  // 8. output projection -> d_out
  launch_gemm(stream, ctx, WoT, out, nullptr, bo, nullptr,
              nullptr, 0, nullptr, 0, nullptr, nullptr, 0, 0,
              NT, Dd, Dd, Dd, Dd, Dd, 0, 0, 0, 1, 0);
}